// Round 4
// baseline (920.449 us; speedup 1.0000x reference)
//
#include <hip/hip_runtime.h>

#define T_TOK 8192
#define D_DIM 1024
#define E_NUM 32
#define K_TOP 4
#define CAP 1280
#define I_DIM 512

#define BM 128
#define BN 128
#define BK 32

typedef float f32x4 __attribute__((ext_vector_type(4)));
typedef short s16x8 __attribute__((ext_vector_type(8)));

static __device__ __forceinline__ unsigned short f2bf(float f) {
    unsigned int u = __float_as_uint(f);
    unsigned int r = (u + 0x7fffu + ((u >> 16) & 1u)) >> 16;
    return (unsigned short)r;
}
static __device__ __forceinline__ float bf2f(unsigned short s) {
    return __uint_as_float(((unsigned int)s) << 16);
}

// ---------------- fp32 -> bf16 pre-convert (x, gate_w, up_w, down_w) ----------------
#define X_F4  2097152L
#define GW_F4 4194304L
__global__ __launch_bounds__(256) void cvt_kernel(
    const float* __restrict__ x, const float* __restrict__ gw,
    const float* __restrict__ uw, const float* __restrict__ dw,
    unsigned short* __restrict__ xbf, unsigned short* __restrict__ gbf,
    unsigned short* __restrict__ ubf, unsigned short* __restrict__ dbf) {
    long i = (long)blockIdx.x * 256 + threadIdx.x;   // float4 index
    const float* src; unsigned short* dst; long off;
    if (i < X_F4)                { src = x;  dst = xbf; off = i; }
    else if (i < X_F4 + GW_F4)   { src = gw; dst = gbf; off = i - X_F4; }
    else if (i < X_F4 + 2*GW_F4) { src = uw; dst = ubf; off = i - X_F4 - GW_F4; }
    else                         { src = dw; dst = dbf; off = i - X_F4 - 2*GW_F4; }
    float4 v = ((const float4*)src)[off];
    ushort4 b;
    b.x = f2bf(v.x); b.y = f2bf(v.y); b.z = f2bf(v.z); b.w = f2bf(v.w);
    ((ushort4*)dst)[off] = b;
}

// ---------------- router: logits = x @ router_w^T (fp32 exact) ----------------
__global__ __launch_bounds__(256) void router_kernel(
    const float* __restrict__ x, const float* __restrict__ rw,
    float* __restrict__ logits) {
    int t = (blockIdx.x * 256 + threadIdx.x) >> 6;   // one wave per token
    int lane = threadIdx.x & 63;
    const float* xr = x + (size_t)t * D_DIM;
    float xf[16];
#pragma unroll
    for (int j = 0; j < 16; ++j) xf[j] = xr[lane + 64 * j];
#pragma unroll 1
    for (int e = 0; e < E_NUM; ++e) {
        const float* wr = rw + (size_t)e * D_DIM;
        float acc = 0.f;
#pragma unroll
        for (int j = 0; j < 16; ++j) acc = fmaf(xf[j], wr[lane + 64 * j], acc);
#pragma unroll
        for (int off = 32; off; off >>= 1) acc += __shfl_xor(acc, off);
        if (lane == 0) logits[(size_t)t * E_NUM + e] = acc;
    }
}

// ------------- softmax + top-4 + renorm + slot assignment (wave/token) -------------
__global__ __launch_bounds__(256) void topk_kernel(
    const float* __restrict__ logits,
    int* __restrict__ counts, int* __restrict__ rowtok,
    int* __restrict__ tokslot, float* __restrict__ tokcoef) {
    int t = (blockIdx.x * 256 + threadIdx.x) >> 6;
    int lane = threadIdx.x & 63;
    float v = -1e30f;
    if (lane < E_NUM) v = logits[(size_t)t * E_NUM + lane];
    float m = v;
#pragma unroll
    for (int off = 16; off; off >>= 1) m = fmaxf(m, __shfl_xor(m, off));
    float p = (lane < E_NUM) ? __expf(v - m) : 0.0f;
    float s = p;
#pragma unroll
    for (int off = 16; off; off >>= 1) s += __shfl_xor(s, off);
    p /= s;

    float cur = p;
    float wv[K_TOP];
    int sel[K_TOP];
#pragma unroll
    for (int k = 0; k < K_TOP; ++k) {
        float mv = cur;
        int mi = lane;
#pragma unroll
        for (int off = 16; off; off >>= 1) {
            float ov = __shfl_xor(mv, off);
            int oi = __shfl_xor(mi, off);
            if (ov > mv || (ov == mv && oi < mi)) { mv = ov; mi = oi; }
        }
        wv[k] = mv; sel[k] = mi;
        if (lane == mi) cur = -1.0f;
    }
    if (lane == 0) {
        float inv = 1.0f / (wv[0] + wv[1] + wv[2] + wv[3]);
#pragma unroll
        for (int k = 0; k < K_TOP; ++k) {
            int slot = atomicAdd(&counts[sel[k]], 1);
            if (slot < CAP) {
                rowtok[sel[k] * CAP + slot] = t;
                tokslot[t * K_TOP + k] = sel[k] * CAP + slot;
            } else {
                tokslot[t * K_TOP + k] = -1;
            }
            tokcoef[t * K_TOP + k] = wv[k] * inv;
        }
    }
}

static __device__ __forceinline__ void mfma_gu(
    const s16x8 a[4], const s16x8 g[4], const s16x8 u[4],
    f32x4 accg[4][4], f32x4 accu[4][4]) {
#pragma unroll
    for (int mi = 0; mi < 4; ++mi)
#pragma unroll
        for (int ni = 0; ni < 4; ++ni) {
            accg[mi][ni] = __builtin_amdgcn_mfma_f32_16x16x32_bf16(a[mi], g[ni], accg[mi][ni], 0, 0, 0);
            accu[mi][ni] = __builtin_amdgcn_mfma_f32_16x16x32_bf16(a[mi], u[ni], accu[mi][ni], 0, 0, 0);
        }
}

// ------- gate+up fused GEMM: register fragments straight from L2/L3, no LDS, no barriers -------
__global__ __launch_bounds__(256) void gateup_kernel(
    const unsigned short* __restrict__ xbf,
    const unsigned short* __restrict__ gbf, const unsigned short* __restrict__ ubf,
    const int* __restrict__ counts, const int* __restrict__ rowtok,
    unsigned short* __restrict__ h_ws) {
    int bid = blockIdx.x;
    int e = bid / ((CAP / BM) * (I_DIM / BN));
    int rem = bid % ((CAP / BM) * (I_DIM / BN));
    int mt = rem / (I_DIM / BN);
    int nt = rem % (I_DIM / BN);
    int n_e = counts[e]; if (n_e > CAP) n_e = CAP;
    if (mt * BM >= n_e) return;

    int tid = threadIdx.x, lane = tid & 63, wv = tid >> 6;
    int wm = (wv >> 1) * 64;
    int wn = (wv & 1) * 64;
    int colsel = (lane >> 4) * 8;
    int lrow = lane & 15;

    // per-lane fragment pointers
    const unsigned short* pA[4];
#pragma unroll
    for (int mi = 0; mi < 4; ++mi) {
        int r = mt * BM + wm + mi * 16 + lrow;
        int rr = (r < n_e) ? r : (n_e - 1);
        int tok = rowtok[e * CAP + rr];
        pA[mi] = xbf + (size_t)tok * D_DIM + colsel;
    }
    const unsigned short* pG[4];
    const unsigned short* pU[4];
#pragma unroll
    for (int ni = 0; ni < 4; ++ni) {
        size_t wrow = (size_t)e * I_DIM + nt * BN + wn + ni * 16 + lrow;
        pG[ni] = gbf + wrow * D_DIM + colsel;
        pU[ni] = ubf + wrow * D_DIM + colsel;
    }

    f32x4 accg[4][4] = {};
    f32x4 accu[4][4] = {};

    s16x8 aC[4], gC[4], uC[4], aN[4], gN[4], uN[4];
#pragma unroll
    for (int i = 0; i < 4; ++i) {
        aC[i] = *(const s16x8*)(pA[i]);
        gC[i] = *(const s16x8*)(pG[i]);
        uC[i] = *(const s16x8*)(pU[i]);
    }

#pragma unroll 2
    for (int kk = 0; kk < D_DIM; kk += 2 * BK) {
#pragma unroll
        for (int i = 0; i < 4; ++i) {
            aN[i] = *(const s16x8*)(pA[i] + kk + BK);
            gN[i] = *(const s16x8*)(pG[i] + kk + BK);
            uN[i] = *(const s16x8*)(pU[i] + kk + BK);
        }
        mfma_gu(aC, gC, uC, accg, accu);
#pragma unroll
        for (int i = 0; i < 4; ++i) {   // last of these overfetches 16B past row end (ws-internal, safe)
            aC[i] = *(const s16x8*)(pA[i] + kk + 2 * BK);
            gC[i] = *(const s16x8*)(pG[i] + kk + 2 * BK);
            uC[i] = *(const s16x8*)(pU[i] + kk + 2 * BK);
        }
        mfma_gu(aN, gN, uN, accg, accu);
    }

    int rq = (lane >> 4) * 4;
    int cq = lane & 15;
#pragma unroll
    for (int mi = 0; mi < 4; ++mi)
#pragma unroll
        for (int ni = 0; ni < 4; ++ni)
#pragma unroll
            for (int r = 0; r < 4; ++r) {
                int grow = mt * BM + wm + mi * 16 + rq + r;
                if (grow < n_e) {
                    float g = accg[mi][ni][r];
                    float hv = g / (1.0f + __expf(-g)) * accu[mi][ni][r];
                    int icol = nt * BN + wn + ni * 16 + cq;
                    h_ws[((size_t)e * CAP + grow) * I_DIM + icol] = f2bf(hv);
                }
            }
}

// ---------- down GEMM: register fragments, no LDS, no barriers -> y_ws bf16 ----------
__global__ __launch_bounds__(256) void down_kernel(
    const unsigned short* __restrict__ h_ws, const unsigned short* __restrict__ dbf,
    const int* __restrict__ counts, unsigned short* __restrict__ y_ws) {
    int bid = blockIdx.x;
    int e = bid / ((CAP / BM) * (D_DIM / BN));
    int rem = bid % ((CAP / BM) * (D_DIM / BN));
    int mt = rem / (D_DIM / BN);
    int nt = rem % (D_DIM / BN);
    int n_e = counts[e]; if (n_e > CAP) n_e = CAP;
    if (mt * BM >= n_e) return;

    int tid = threadIdx.x, lane = tid & 63, wv = tid >> 6;
    int wm = (wv >> 1) * 64;
    int wn = (wv & 1) * 64;
    int colsel = (lane >> 4) * 8;
    int lrow = lane & 15;

    const unsigned short* pA[4];
    const unsigned short* pB[4];
#pragma unroll
    for (int i = 0; i < 4; ++i) {
        pA[i] = h_ws + ((size_t)e * CAP + mt * BM + wm + i * 16 + lrow) * I_DIM + colsel;
        pB[i] = dbf + ((size_t)e * D_DIM + nt * BN + wn + i * 16 + lrow) * I_DIM + colsel;
    }

    f32x4 acc[4][4] = {};
    s16x8 aC[4], bC[4], aN[4], bN[4];
#pragma unroll
    for (int i = 0; i < 4; ++i) {
        aC[i] = *(const s16x8*)(pA[i]);
        bC[i] = *(const s16x8*)(pB[i]);
    }

#pragma unroll 2
    for (int kk = 0; kk < I_DIM; kk += 2 * BK) {
#pragma unroll
        for (int i = 0; i < 4; ++i) {
            aN[i] = *(const s16x8*)(pA[i] + kk + BK);
            bN[i] = *(const s16x8*)(pB[i] + kk + BK);
        }
#pragma unroll
        for (int mi = 0; mi < 4; ++mi)
#pragma unroll
            for (int ni = 0; ni < 4; ++ni)
                acc[mi][ni] = __builtin_amdgcn_mfma_f32_16x16x32_bf16(aC[mi], bC[ni], acc[mi][ni], 0, 0, 0);
#pragma unroll
        for (int i = 0; i < 4; ++i) {
            aC[i] = *(const s16x8*)(pA[i] + kk + 2 * BK);
            bC[i] = *(const s16x8*)(pB[i] + kk + 2 * BK);
        }
#pragma unroll
        for (int mi = 0; mi < 4; ++mi)
#pragma unroll
            for (int ni = 0; ni < 4; ++ni)
                acc[mi][ni] = __builtin_amdgcn_mfma_f32_16x16x32_bf16(aN[mi], bN[ni], acc[mi][ni], 0, 0, 0);
    }

    int rq = (lane >> 4) * 4;
    int cq = lane & 15;
#pragma unroll
    for (int mi = 0; mi < 4; ++mi)
#pragma unroll
        for (int ni = 0; ni < 4; ++ni)
#pragma unroll
            for (int r = 0; r < 4; ++r) {
                int grow = mt * BM + wm + mi * 16 + rq + r;
                if (grow < n_e) {
                    int dcol = nt * BN + wn + ni * 16 + cq;
                    y_ws[((size_t)e * CAP + grow) * D_DIM + dcol] = f2bf(acc[mi][ni][r]);
                }
            }
}

// ---------------- combine: out[t] = sum_k coef_k * y_ws[slot_k]  (one wave/token) ----------------
__global__ __launch_bounds__(256) void combine_kernel(
    const unsigned short* __restrict__ y_ws,
    const int* __restrict__ tokslot, const float* __restrict__ tokcoef,
    float* __restrict__ out) {
    int t = (blockIdx.x * 256 + threadIdx.x) >> 6;
    int lane = threadIdx.x & 63;
    float acc[16] = {};
#pragma unroll
    for (int k = 0; k < K_TOP; ++k) {
        int slot = tokslot[t * K_TOP + k];           // wave-uniform
        if (slot >= 0) {
            float c = tokcoef[t * K_TOP + k];
            const unsigned short* row = y_ws + (size_t)slot * D_DIM + lane * 16;
            s16x8 v0 = *(const s16x8*)row;
            s16x8 v1 = *(const s16x8*)(row + 8);
#pragma unroll
            for (int j = 0; j < 8; ++j) acc[j]     = fmaf(c, bf2f((unsigned short)v0[j]), acc[j]);
#pragma unroll
            for (int j = 0; j < 8; ++j) acc[8 + j] = fmaf(c, bf2f((unsigned short)v1[j]), acc[8 + j]);
        }
    }
    float* o = out + (size_t)t * D_DIM + lane * 16;
#pragma unroll
    for (int j = 0; j < 4; ++j)
        ((float4*)o)[j] = make_float4(acc[4 * j], acc[4 * j + 1], acc[4 * j + 2], acc[4 * j + 3]);
}

extern "C" void kernel_launch(void* const* d_in, const int* in_sizes, int n_in,
                              void* d_out, int out_size, void* d_ws, size_t ws_size,
                              hipStream_t stream) {
    const float* x  = (const float*)d_in[0];
    const float* rw = (const float*)d_in[1];
    const float* gw = (const float*)d_in[2];
    const float* uw = (const float*)d_in[3];
    const float* dw = (const float*)d_in[4];
    float* out = (float*)d_out;
    float* logits = out + (size_t)T_TOK * D_DIM;

    char* ws = (char*)d_ws;
    size_t off = 0;
    // region A (84 MB): xbf|gbf|ubf — dead after gateup; aliased by y_ws afterwards
    unsigned short* xbf = (unsigned short*)(ws + off); off += (size_t)T_TOK * D_DIM * 2;          // 16.78 MB
    unsigned short* gbf = (unsigned short*)(ws + off); off += (size_t)E_NUM * I_DIM * D_DIM * 2;  // 33.55 MB
    unsigned short* ubf = (unsigned short*)(ws + off); off += (size_t)E_NUM * I_DIM * D_DIM * 2;  // 33.55 MB
    unsigned short* y_ws = xbf;  // [E, CAP, D] bf16 = 83.89 MB, exactly region A
    unsigned short* dbf = (unsigned short*)(ws + off); off += (size_t)E_NUM * D_DIM * I_DIM * 2;  // 33.55 MB
    unsigned short* h_ws = (unsigned short*)(ws + off); off += (size_t)E_NUM * CAP * I_DIM * 2;   // 41.94 MB
    int* counts = (int*)(ws + off); off += 256;
    int* rowtok = (int*)(ws + off); off += (size_t)E_NUM * CAP * 4;
    int* tokslot = (int*)(ws + off); off += (size_t)T_TOK * K_TOP * 4;
    float* tokcoef = (float*)(ws + off); off += (size_t)T_TOK * K_TOP * 4;
    off += 4096;  // overfetch slack

    hipMemsetAsync(counts, 0, E_NUM * 4, stream);

    cvt_kernel<<<(int)((X_F4 + 3 * GW_F4) / 256), 256, 0, stream>>>(x, gw, uw, dw, xbf, gbf, ubf, dbf);
    router_kernel<<<T_TOK / 4, 256, 0, stream>>>(x, rw, logits);
    topk_kernel<<<T_TOK / 4, 256, 0, stream>>>(logits, counts, rowtok, tokslot, tokcoef);
    gateup_kernel<<<E_NUM * (CAP / BM) * (I_DIM / BN), 256, 0, stream>>>(xbf, gbf, ubf, counts, rowtok, h_ws);
    down_kernel<<<E_NUM * (CAP / BM) * (D_DIM / BN), 256, 0, stream>>>(h_ws, dbf, counts, y_ws);
    combine_kernel<<<T_TOK / 4, 256, 0, stream>>>(y_ws, tokslot, tokcoef, out);
}

// Round 5
// 728.238 us; speedup vs baseline: 1.2639x; 1.2639x over previous
//
#include <hip/hip_runtime.h>

#define T_TOK 8192
#define D_DIM 1024
#define E_NUM 32
#define K_TOP 4
#define CAP 1280
#define I_DIM 512

#define BM 128
#define BN 128
#define BK 32

typedef float f32x4 __attribute__((ext_vector_type(4)));
typedef short s16x8 __attribute__((ext_vector_type(8)));

static __device__ __forceinline__ unsigned short f2bf(float f) {
    unsigned int u = __float_as_uint(f);
    unsigned int r = (u + 0x7fffu + ((u >> 16) & 1u)) >> 16;
    return (unsigned short)r;
}
static __device__ __forceinline__ float bf2f(unsigned short s) {
    return __uint_as_float(((unsigned int)s) << 16);
}

// async 16B global->LDS (dest = wave-uniform base + lane*16)
static __device__ __forceinline__ void gload16(const unsigned short* g, unsigned short* l) {
    __builtin_amdgcn_global_load_lds(
        (const __attribute__((address_space(1))) unsigned int*)g,
        (__attribute__((address_space(3))) unsigned int*)l,
        16, 0, 0);
}

// ---------------- fp32 -> bf16 pre-convert (x, gate_w, up_w, down_w) ----------------
#define X_F4  2097152L
#define GW_F4 4194304L
__global__ __launch_bounds__(256) void cvt_kernel(
    const float* __restrict__ x, const float* __restrict__ gw,
    const float* __restrict__ uw, const float* __restrict__ dw,
    unsigned short* __restrict__ xbf, unsigned short* __restrict__ gbf,
    unsigned short* __restrict__ ubf, unsigned short* __restrict__ dbf) {
    long i = (long)blockIdx.x * 256 + threadIdx.x;   // float4 index
    const float* src; unsigned short* dst; long off;
    if (i < X_F4)                { src = x;  dst = xbf; off = i; }
    else if (i < X_F4 + GW_F4)   { src = gw; dst = gbf; off = i - X_F4; }
    else if (i < X_F4 + 2*GW_F4) { src = uw; dst = ubf; off = i - X_F4 - GW_F4; }
    else                         { src = dw; dst = dbf; off = i - X_F4 - 2*GW_F4; }
    float4 v = ((const float4*)src)[off];
    ushort4 b;
    b.x = f2bf(v.x); b.y = f2bf(v.y); b.z = f2bf(v.z); b.w = f2bf(v.w);
    ((ushort4*)dst)[off] = b;
}

// ---------------- router: logits = x @ router_w^T (fp32 exact) ----------------
__global__ __launch_bounds__(256) void router_kernel(
    const float* __restrict__ x, const float* __restrict__ rw,
    float* __restrict__ logits) {
    int t = (blockIdx.x * 256 + threadIdx.x) >> 6;   // one wave per token
    int lane = threadIdx.x & 63;
    const float* xr = x + (size_t)t * D_DIM;
    float xf[16];
#pragma unroll
    for (int j = 0; j < 16; ++j) xf[j] = xr[lane + 64 * j];
#pragma unroll 1
    for (int e = 0; e < E_NUM; ++e) {
        const float* wr = rw + (size_t)e * D_DIM;
        float acc = 0.f;
#pragma unroll
        for (int j = 0; j < 16; ++j) acc = fmaf(xf[j], wr[lane + 64 * j], acc);
#pragma unroll
        for (int off = 32; off; off >>= 1) acc += __shfl_xor(acc, off);
        if (lane == 0) logits[(size_t)t * E_NUM + e] = acc;
    }
}

// ------------- softmax + top-4 + renorm + slot assignment (wave/token) -------------
__global__ __launch_bounds__(256) void topk_kernel(
    const float* __restrict__ logits,
    int* __restrict__ counts, int* __restrict__ rowtok,
    int* __restrict__ tokslot, float* __restrict__ tokcoef) {
    int t = (blockIdx.x * 256 + threadIdx.x) >> 6;
    int lane = threadIdx.x & 63;
    float v = -1e30f;
    if (lane < E_NUM) v = logits[(size_t)t * E_NUM + lane];
    float m = v;
#pragma unroll
    for (int off = 16; off; off >>= 1) m = fmaxf(m, __shfl_xor(m, off));
    float p = (lane < E_NUM) ? __expf(v - m) : 0.0f;
    float s = p;
#pragma unroll
    for (int off = 16; off; off >>= 1) s += __shfl_xor(s, off);
    p /= s;

    float cur = p;
    float wv[K_TOP];
    int sel[K_TOP];
#pragma unroll
    for (int k = 0; k < K_TOP; ++k) {
        float mv = cur;
        int mi = lane;
#pragma unroll
        for (int off = 16; off; off >>= 1) {
            float ov = __shfl_xor(mv, off);
            int oi = __shfl_xor(mi, off);
            if (ov > mv || (ov == mv && oi < mi)) { mv = ov; mi = oi; }
        }
        wv[k] = mv; sel[k] = mi;
        if (lane == mi) cur = -1.0f;
    }
    if (lane == 0) {
        float inv = 1.0f / (wv[0] + wv[1] + wv[2] + wv[3]);
#pragma unroll
        for (int k = 0; k < K_TOP; ++k) {
            int slot = atomicAdd(&counts[sel[k]], 1);
            if (slot < CAP) {
                rowtok[sel[k] * CAP + slot] = t;
                tokslot[t * K_TOP + k] = sel[k] * CAP + slot;
            } else {
                tokslot[t * K_TOP + k] = -1;
            }
            tokcoef[t * K_TOP + k] = wv[k] * inv;
        }
    }
}

// ------- gate+up GEMM fused (bf16, global_load_lds, dbuf, XCD-swizzled), h = silu(g)*u -------
__global__ __launch_bounds__(256) void gateup_kernel(
    const unsigned short* __restrict__ xbf,
    const unsigned short* __restrict__ gbf, const unsigned short* __restrict__ ubf,
    const int* __restrict__ counts, const int* __restrict__ rowtok,
    unsigned short* __restrict__ h_ws) {
    // XCD-aware remap: all 40 tiles of expert e land on XCD e&7 (bid%8 == XCD, m09).
    // slot order: mt outer, nt inner -> live L2 set per XCD = one expert's 4 B-tiles (2MB) + A-tile.
    int bid = blockIdx.x;
    int xcd = bid & 7;
    int slot = bid >> 3;                 // [0,160)
    int e = xcd + 8 * (slot / 40);
    int r = slot % 40;
    int mt = r >> 2;                     // [0,10)
    int nt = r & 3;                      // [0,4)
    int n_e = counts[e]; if (n_e > CAP) n_e = CAP;
    if (mt * BM >= n_e) return;

    __shared__ unsigned short As[2][BM * BK];   // ping-pong
    __shared__ unsigned short Bg[2][BM * BK];
    __shared__ unsigned short Bu[2][BM * BK];
    __shared__ int toks[BM];

    int tid = threadIdx.x, lane = tid & 63, wv = tid >> 6;
    if (tid < BM) {
        int rr = mt * BM + tid;
        toks[tid] = (rr < n_e) ? rowtok[e * CAP + rr] : rowtok[e * CAP];
    }
    __syncthreads();

    int rA0 = (wv * 2 + 0) * 16 + (lane >> 2);
    int rA1 = rA0 + 16;
    int cst = (lane & 3) * 8;
    const unsigned short* gaA0 = xbf + (size_t)toks[rA0] * D_DIM + cst;
    const unsigned short* gaA1 = xbf + (size_t)toks[rA1] * D_DIM + cst;
    const unsigned short* gaG0 = gbf + ((size_t)e * I_DIM + nt * BN + rA0) * D_DIM + cst;
    const unsigned short* gaG1 = gbf + ((size_t)e * I_DIM + nt * BN + rA1) * D_DIM + cst;
    const unsigned short* gaU0 = ubf + ((size_t)e * I_DIM + nt * BN + rA0) * D_DIM + cst;
    const unsigned short* gaU1 = ubf + ((size_t)e * I_DIM + nt * BN + rA1) * D_DIM + cst;
    int l0 = (wv * 2 + 0) * 512;
    int l1 = (wv * 2 + 1) * 512;

    int wm = (wv >> 1) * 64;
    int wn = (wv & 1) * 64;

    f32x4 accg[4][4] = {};
    f32x4 accu[4][4] = {};

    gload16(gaA0, &As[0][l0]); gload16(gaA1, &As[0][l1]);
    gload16(gaG0, &Bg[0][l0]); gload16(gaG1, &Bg[0][l1]);
    gload16(gaU0, &Bu[0][l0]); gload16(gaU1, &Bu[0][l1]);

    for (int kk = 0; kk < D_DIM; kk += BK) {
        int p = (kk >> 5) & 1;
        __syncthreads();   // drains loads for parity p

        if (kk + BK < D_DIM) {   // prefetch next tile into parity p^1
            int q = p ^ 1, k2 = kk + BK;
            gload16(gaA0 + k2, &As[q][l0]); gload16(gaA1 + k2, &As[q][l1]);
            gload16(gaG0 + k2, &Bg[q][l0]); gload16(gaG1 + k2, &Bg[q][l1]);
            gload16(gaU0 + k2, &Bu[q][l0]); gload16(gaU1 + k2, &Bu[q][l1]);
        }

        s16x8 af[4], bgf[4], buf[4];
#pragma unroll
        for (int mi = 0; mi < 4; ++mi)
            af[mi] = *(const s16x8*)&As[p][(wm + mi * 16 + (lane & 15)) * BK + (lane >> 4) * 8];
#pragma unroll
        for (int ni = 0; ni < 4; ++ni) {
            bgf[ni] = *(const s16x8*)&Bg[p][(wn + ni * 16 + (lane & 15)) * BK + (lane >> 4) * 8];
            buf[ni] = *(const s16x8*)&Bu[p][(wn + ni * 16 + (lane & 15)) * BK + (lane >> 4) * 8];
        }
#pragma unroll
        for (int mi = 0; mi < 4; ++mi)
#pragma unroll
            for (int ni = 0; ni < 4; ++ni) {
                accg[mi][ni] = __builtin_amdgcn_mfma_f32_16x16x32_bf16(af[mi], bgf[ni], accg[mi][ni], 0, 0, 0);
                accu[mi][ni] = __builtin_amdgcn_mfma_f32_16x16x32_bf16(af[mi], buf[ni], accu[mi][ni], 0, 0, 0);
            }
    }

    int rq = (lane >> 4) * 4;
    int cq = lane & 15;
#pragma unroll
    for (int mi = 0; mi < 4; ++mi)
#pragma unroll
        for (int ni = 0; ni < 4; ++ni)
#pragma unroll
            for (int rr = 0; rr < 4; ++rr) {
                int grow = mt * BM + wm + mi * 16 + rq + rr;
                if (grow < n_e) {
                    float g = accg[mi][ni][rr];
                    float hv = g / (1.0f + __expf(-g)) * accu[mi][ni][rr];
                    int icol = nt * BN + wn + ni * 16 + cq;
                    h_ws[((size_t)e * CAP + grow) * I_DIM + icol] = f2bf(hv);
                }
            }
}

// ---------- down GEMM (bf16, global_load_lds, dbuf, XCD-swizzled) -> y_ws bf16 ----------
__global__ __launch_bounds__(256) void down_kernel(
    const unsigned short* __restrict__ h_ws, const unsigned short* __restrict__ dbf,
    const int* __restrict__ counts, unsigned short* __restrict__ y_ws) {
    int bid = blockIdx.x;
    int xcd = bid & 7;
    int slot = bid >> 3;                 // [0,320)
    int e = xcd + 8 * (slot / 80);
    int r = slot % 80;
    int mt = r >> 3;                     // [0,10)
    int nt = r & 7;                      // [0,8)
    int n_e = counts[e]; if (n_e > CAP) n_e = CAP;
    if (mt * BM >= n_e) return;

    __shared__ unsigned short As[2][BM * BK];
    __shared__ unsigned short Bd[2][BM * BK];

    int tid = threadIdx.x, lane = tid & 63, wv = tid >> 6;

    int rA0 = (wv * 2 + 0) * 16 + (lane >> 2);
    int rA1 = rA0 + 16;
    int cst = (lane & 3) * 8;
    const unsigned short* gaA0 = h_ws + ((size_t)e * CAP + mt * BM + rA0) * I_DIM + cst;
    const unsigned short* gaA1 = h_ws + ((size_t)e * CAP + mt * BM + rA1) * I_DIM + cst;
    const unsigned short* gaB0 = dbf + ((size_t)e * D_DIM + nt * BN + rA0) * I_DIM + cst;
    const unsigned short* gaB1 = dbf + ((size_t)e * D_DIM + nt * BN + rA1) * I_DIM + cst;
    int l0 = (wv * 2 + 0) * 512;
    int l1 = (wv * 2 + 1) * 512;

    int wm = (wv >> 1) * 64;
    int wn = (wv & 1) * 64;

    f32x4 acc[4][4] = {};

    gload16(gaA0, &As[0][l0]); gload16(gaA1, &As[0][l1]);
    gload16(gaB0, &Bd[0][l0]); gload16(gaB1, &Bd[0][l1]);

    for (int kk = 0; kk < I_DIM; kk += BK) {
        int p = (kk >> 5) & 1;
        __syncthreads();

        if (kk + BK < I_DIM) {
            int q = p ^ 1, k2 = kk + BK;
            gload16(gaA0 + k2, &As[q][l0]); gload16(gaA1 + k2, &As[q][l1]);
            gload16(gaB0 + k2, &Bd[q][l0]); gload16(gaB1 + k2, &Bd[q][l1]);
        }

        s16x8 af[4], bf[4];
#pragma unroll
        for (int mi = 0; mi < 4; ++mi)
            af[mi] = *(const s16x8*)&As[p][(wm + mi * 16 + (lane & 15)) * BK + (lane >> 4) * 8];
#pragma unroll
        for (int ni = 0; ni < 4; ++ni)
            bf[ni] = *(const s16x8*)&Bd[p][(wn + ni * 16 + (lane & 15)) * BK + (lane >> 4) * 8];
#pragma unroll
        for (int mi = 0; mi < 4; ++mi)
#pragma unroll
            for (int ni = 0; ni < 4; ++ni)
                acc[mi][ni] = __builtin_amdgcn_mfma_f32_16x16x32_bf16(af[mi], bf[ni], acc[mi][ni], 0, 0, 0);
    }

    int rq = (lane >> 4) * 4;
    int cq = lane & 15;
#pragma unroll
    for (int mi = 0; mi < 4; ++mi)
#pragma unroll
        for (int ni = 0; ni < 4; ++ni)
#pragma unroll
            for (int rr = 0; rr < 4; ++rr) {
                int grow = mt * BM + wm + mi * 16 + rq + rr;
                if (grow < n_e) {
                    int dcol = nt * BN + wn + ni * 16 + cq;
                    y_ws[((size_t)e * CAP + grow) * D_DIM + dcol] = f2bf(acc[mi][ni][rr]);
                }
            }
}

// ---------------- combine: out[t] = sum_k coef_k * y_ws[slot_k]  (one wave/token) ----------------
__global__ __launch_bounds__(256) void combine_kernel(
    const unsigned short* __restrict__ y_ws,
    const int* __restrict__ tokslot, const float* __restrict__ tokcoef,
    float* __restrict__ out) {
    int t = (blockIdx.x * 256 + threadIdx.x) >> 6;
    int lane = threadIdx.x & 63;
    float acc[16] = {};
#pragma unroll
    for (int k = 0; k < K_TOP; ++k) {
        int slot = tokslot[t * K_TOP + k];           // wave-uniform
        if (slot >= 0) {
            float c = tokcoef[t * K_TOP + k];
            const unsigned short* row = y_ws + (size_t)slot * D_DIM + lane * 16;
            s16x8 v0 = *(const s16x8*)row;
            s16x8 v1 = *(const s16x8*)(row + 8);
#pragma unroll
            for (int j = 0; j < 8; ++j) acc[j]     = fmaf(c, bf2f((unsigned short)v0[j]), acc[j]);
#pragma unroll
            for (int j = 0; j < 8; ++j) acc[8 + j] = fmaf(c, bf2f((unsigned short)v1[j]), acc[8 + j]);
        }
    }
    float* o = out + (size_t)t * D_DIM + lane * 16;
#pragma unroll
    for (int j = 0; j < 4; ++j)
        ((float4*)o)[j] = make_float4(acc[4 * j], acc[4 * j + 1], acc[4 * j + 2], acc[4 * j + 3]);
}

extern "C" void kernel_launch(void* const* d_in, const int* in_sizes, int n_in,
                              void* d_out, int out_size, void* d_ws, size_t ws_size,
                              hipStream_t stream) {
    const float* x  = (const float*)d_in[0];
    const float* rw = (const float*)d_in[1];
    const float* gw = (const float*)d_in[2];
    const float* uw = (const float*)d_in[3];
    const float* dw = (const float*)d_in[4];
    float* out = (float*)d_out;
    float* logits = out + (size_t)T_TOK * D_DIM;

    char* ws = (char*)d_ws;
    size_t off = 0;
    // region A (84 MB): xbf|gbf|ubf — dead after gateup; aliased by y_ws afterwards
    unsigned short* xbf = (unsigned short*)(ws + off); off += (size_t)T_TOK * D_DIM * 2;          // 16.78 MB
    unsigned short* gbf = (unsigned short*)(ws + off); off += (size_t)E_NUM * I_DIM * D_DIM * 2;  // 33.55 MB
    unsigned short* ubf = (unsigned short*)(ws + off); off += (size_t)E_NUM * I_DIM * D_DIM * 2;  // 33.55 MB
    unsigned short* y_ws = xbf;  // [E, CAP, D] bf16 = 83.89 MB, exactly region A
    unsigned short* dbf = (unsigned short*)(ws + off); off += (size_t)E_NUM * D_DIM * I_DIM * 2;  // 33.55 MB
    unsigned short* h_ws = (unsigned short*)(ws + off); off += (size_t)E_NUM * CAP * I_DIM * 2;   // 41.94 MB
    int* counts = (int*)(ws + off); off += 256;
    int* rowtok = (int*)(ws + off); off += (size_t)E_NUM * CAP * 4;
    int* tokslot = (int*)(ws + off); off += (size_t)T_TOK * K_TOP * 4;
    float* tokcoef = (float*)(ws + off); off += (size_t)T_TOK * K_TOP * 4;

    hipMemsetAsync(counts, 0, E_NUM * 4, stream);

    cvt_kernel<<<(int)((X_F4 + 3 * GW_F4) / 256), 256, 0, stream>>>(x, gw, uw, dw, xbf, gbf, ubf, dbf);
    router_kernel<<<T_TOK / 4, 256, 0, stream>>>(x, rw, logits);
    topk_kernel<<<T_TOK / 4, 256, 0, stream>>>(logits, counts, rowtok, tokslot, tokcoef);
    gateup_kernel<<<E_NUM * (CAP / BM) * (I_DIM / BN), 256, 0, stream>>>(xbf, gbf, ubf, counts, rowtok, h_ws);
    down_kernel<<<E_NUM * (CAP / BM) * (D_DIM / BN), 256, 0, stream>>>(h_ws, dbf, counts, y_ws);
    combine_kernel<<<T_TOK / 4, 256, 0, stream>>>(y_ws, tokslot, tokcoef, out);
}